// Round 4
// baseline (717.259 us; speedup 1.0000x reference)
//
#include <hip/hip_runtime.h>
#include <hip/hip_bf16.h>

// AdaptiveReLULayer: out[b,n,o] = leaky( sum_i x[b,n,i] * weight[idx[b],i,o] + bias[o], 0.2 )
// B=2048, N=256, IN=256, OUT=256, C=1024.  f32 I/O; bf16 MFMA, f32 accum.
//
// R7 change vs R6 (298us; depth-2 pipeline held but +3% only -> depth theory
// dead): the invariant binder is per-round HBM dependence with a strided
// pattern (x k-slices: 128B @ 1KB stride from ~512 blocks).  Re-tile to
// 32x256 output per block (grid = 2048 b x 8 n-tiles):
//   * A (x): 32KB/block loaded ONCE at prologue into af[8] regs (all rounds'
//     A-frags).  ZERO HBM on the K-round path.
//   * B (w): per round = 32 contiguous k-rows x 1KB = sequential 32KB chunk;
//     block scans w[c] 0..256KB purely sequentially.  Reg-staged (R6 proven
//     depth-2 named sets) -> cvt bf16 -> k-permuted B^T in LDS, 16KB/tile,
//     TRIPLE buffered (48KB -> 3 blocks/CU).
//   * k-permutation pi: slot s <-> k = 4s+g.  Contiguous staging gives each
//     thread k-rows {wid,4+wid,..}; pi makes its LDS write one b128.  MFMA
//     is pi-invariant as long as A frags use the SAME pi (A packed stride-4).
//   * LDS layout: o-row pairs of 128B, chunk = (((o&1)<<2)|(p>>3)) ^ key,
//     key = ((o>>1)^(o>>4))&7 -> b128 reads AND writes conflict-free floor.
// w L2 amplification x8 (4.3GB) is the accepted risk / pre-committed
// alternative wall (~150-175us of L2 time).

#define K_DIM 256
#define O_DIM 256

typedef __attribute__((ext_vector_type(8))) __bf16 bf16x8;
typedef __attribute__((ext_vector_type(4))) float f32x4;
typedef __attribute__((ext_vector_type(4))) unsigned int u32x4;

__device__ __forceinline__ f32x4 MFMA(u32x4 a, u32x4 b, f32x4 c) {
    return __builtin_amdgcn_mfma_f32_16x16x32_bf16(
        __builtin_bit_cast(bf16x8, a), __builtin_bit_cast(bf16x8, b), c, 0, 0, 0);
}

__device__ __forceinline__ unsigned pk2(float a, float b) {
    __hip_bfloat16 ha = __float2bfloat16(a);
    __hip_bfloat16 hb = __float2bfloat16(b);
    unsigned short sa, sb;
    __builtin_memcpy(&sa, &ha, 2);
    __builtin_memcpy(&sb, &hb, 2);
    return (unsigned)sa | ((unsigned)sb << 16);
}

// B^T tile byte offset for (o, p); p = k-position 0..31, real k = 4*(p&7)+(p>>3).
__device__ __forceinline__ int bbyte(int o, int p) {
    const int rp  = o >> 1;
    const int raw = ((o & 1) << 2) | (p >> 3);
    const int key = (rp ^ (o >> 4)) & 7;
    return rp * 128 + ((raw ^ key) << 4) + ((p & 7) << 1);
}

__global__ __launch_bounds__(256, 3) void argemm_kernel(
    const float* __restrict__ x,
    const int* __restrict__ idx,
    const float* __restrict__ w,
    const float* __restrict__ bias,
    float* __restrict__ out)
{
    __shared__ __align__(16) char lds[49152];  // 3 x 16KB B^T bf16 tiles

    const int tid = threadIdx.x;
    const int l   = tid & 63;
    const int wid = tid >> 6;
    const int wr  = wid >> 1;   // 16-row half of the 32-row tile
    const int wc  = wid & 1;    // 128-col half of the 256-col tile

    // XCD-chunked swizzle: consecutive logical blocks (same b, 8 n-tiles)
    // land on the same XCD -> w[c] lives in one L2.
    const unsigned bid     = blockIdx.x;
    const unsigned chunk   = gridDim.x >> 3;
    const unsigned logical = (bid & 7u) * chunk + (bid >> 3);
    const int b  = (int)(logical >> 3);
    const int n0 = (int)(logical & 7u) * 32;

    const int g = l >> 4;   // 0..3
    const int i = l & 15;   // 0..15

    const int c = idx[b];
    const float* xb = x + (size_t)b * (256 * 256);
    const float* wb = w + (size_t)c * (256 * 256);

    // ---- B staging: thread owns k-rows {4q+wid}, o-quad l*4 (contig instrs) ----
    const float* wp = wb + l * 4;
    int bW[4];
#pragma unroll
    for (int j = 0; j < 4; ++j)
        bW[j] = bbyte(l * 4 + j, wid * 8);             // p-range [wid*8, wid*8+8)

    // ---- frag read addresses ----
    int bR[8];
#pragma unroll
    for (int n = 0; n < 8; ++n)
        bR[n] = bbyte(wc * 128 + n * 16 + i, g * 8);   // p-range [g*8, g*8+8)

    f32x4 rb[2][8];   // two named staging sets (tile T -> set T&1)

    auto issueB = [&](int t, int s) {
#pragma unroll
        for (int q = 0; q < 8; ++q)
            rb[s][q] = *(const f32x4*)(wp + (size_t)(t * 32 + q * 4 + wid) * 256);
    };
    auto flushB = [&](int T, int s) {
        char* d = (char*)lds + (T % 3) * 16384;
#pragma unroll
        for (int j = 0; j < 4; ++j) {
            u32x4 p;   // slot s (=q) ascending: k = 4s + wid
            p.x = pk2(rb[s][0][j], rb[s][1][j]);
            p.y = pk2(rb[s][2][j], rb[s][3][j]);
            p.z = pk2(rb[s][4][j], rb[s][5][j]);
            p.w = pk2(rb[s][6][j], rb[s][7][j]);
            *(u32x4*)(d + bW[j]) = p;
        }
    };

    // ---- prologue: B tiles 0,1 in flight; A loaded once into af[8] ----
    issueB(0, 0);
    __builtin_amdgcn_sched_barrier(0);
    issueB(1, 1);
    __builtin_amdgcn_sched_barrier(0);

    // A: row (n0 + wr*16 + i), k-slots s -> k = t*32 + 4s + g (pi-permuted)
    const float* xrow = xb + (n0 + wr * 16 + i) * 256 + g;
    u32x4 af[8];
#pragma unroll
    for (int tb = 0; tb < 2; ++tb) {
        float av[4][8];
#pragma unroll
        for (int t4 = 0; t4 < 4; ++t4)
#pragma unroll
            for (int s = 0; s < 8; ++s)
                av[t4][s] = xrow[(tb * 4 + t4) * 32 + s * 4];
#pragma unroll
        for (int t4 = 0; t4 < 4; ++t4) {
            u32x4 a;
            a.x = pk2(av[t4][0], av[t4][1]);
            a.y = pk2(av[t4][2], av[t4][3]);
            a.z = pk2(av[t4][4], av[t4][5]);
            a.w = pk2(av[t4][6], av[t4][7]);
            af[tb * 4 + t4] = a;
        }
    }

    flushB(0, 0);                      // set0 arrived (counted vmcnt)
    issueB(2, 0);
    __builtin_amdgcn_sched_barrier(0);
    asm volatile("s_waitcnt lgkmcnt(0)" ::: "memory");
    __builtin_amdgcn_sched_barrier(0);
    __builtin_amdgcn_s_barrier();

    f32x4 acc[8];
#pragma unroll
    for (int n = 0; n < 8; ++n)
        acc[n] = (f32x4){0.f, 0.f, 0.f, 0.f};

    // ---- K loop: 8 rounds, one barrier each; rounds depend only on L2-resident w ----
#pragma unroll
    for (int t = 0; t < 8; ++t) {
        const char* buf = (const char*)lds + (t % 3) * 16384;
#pragma unroll
        for (int n = 0; n < 8; ++n) {
            const u32x4 bq = *(const u32x4*)(buf + bR[n]);
            acc[n] = MFMA(af[t], bq, acc[n]);
        }

        if (t < 7) {
            flushB(t + 1, (t + 1) & 1);   // loads issued 2 rounds ago
            if (t < 5) {
                issueB(t + 3, (t + 1) & 1);
                __builtin_amdgcn_sched_barrier(0);   // forbid load sinking (R5 lesson)
            }
            asm volatile("s_waitcnt lgkmcnt(0)" ::: "memory");
            __builtin_amdgcn_sched_barrier(0);
            __builtin_amdgcn_s_barrier();
        }
    }

    // ---- epilogue: bias + LeakyReLU(0.2), f32 store ----
    float biasf[8];
#pragma unroll
    for (int n = 0; n < 8; ++n)
        biasf[n] = bias[wc * 128 + n * 16 + i];

    float* ob = out + (size_t)b * (256 * 256);
#pragma unroll
    for (int n = 0; n < 8; ++n) {
#pragma unroll
        for (int r = 0; r < 4; ++r) {
            const int row = n0 + wr * 16 + g * 4 + r;
            float v = acc[n][r] + biasf[n];
            v = (v >= 0.f) ? v : 0.2f * v;
            ob[row * 256 + wc * 128 + n * 16 + i] = v;
        }
    }
}

extern "C" void kernel_launch(void* const* d_in, const int* in_sizes, int n_in,
                              void* d_out, int out_size, void* d_ws, size_t ws_size,
                              hipStream_t stream) {
    const float* x    = (const float*)d_in[0];
    const int*   idx  = (const int*)d_in[1];
    const float* w    = (const float*)d_in[2];
    const float* bias = (const float*)d_in[3];
    float*       out  = (float*)d_out;
    (void)d_ws; (void)ws_size; (void)n_in; (void)out_size;

    const int B = in_sizes[1];          // 2048
    dim3 grid((unsigned)(B * 8)), block(256);
    hipLaunchKernelGGL(argemm_kernel, grid, block, 0, stream, x, idx, w, bias, out);
}

// Round 5
// 294.783 us; speedup vs baseline: 2.4332x; 2.4332x over previous
//
#include <hip/hip_runtime.h>
#include <hip/hip_bf16.h>

// AdaptiveReLULayer: out[b,n,o] = leaky( sum_i x[b,n,i] * weight[idx[b],i,o] + bias[o], 0.2 )
// B=2048, N=256, IN=256, OUT=256, C=1024.  f32 I/O; bf16 MFMA, f32 accum.
//
// R8 vs R6 (298us best) / R7 (717us, pipeline collapsed again, VGPR=84):
// ledger: depth-1 = 307, depth-2 held = 298, collapsed = 468/717. BW pinned
// at ~3.6 TB/s across all -> supply-limited by the x HBM PATTERN (128B
// k-slices @ 1KB stride from ~512 blocks). R8 single-variable change vs R6:
// make the x stream purely sequential.
//   * tile 64 rows x 256 o (grid = 2048*4, no x sharing between blocks)
//   * A (x): full 64x256 panel staged ONCE in prologue -- 16 fully-coalesced
//     1KB-per-instruction row reads per wave -> bf16 swizzled LDS panel 32KB.
//     ZERO x-HBM on the K-round path; per-block x read = contiguous 64KB.
//   * B (w): R6's exact proven depth-2 machinery (named reg sets, swz layout,
//     b128 frag reads, sched_barrier anti-sinking, lgkm+s_barrier per round),
//     widened to 256 o: 16KB/buf, double-buffered.  w is L3/L2-resident.
//   * LDS = 32KB A + 2x16KB B = 64KB static exactly; 2 blocks/CU.
// A-panel layout: row r = 512B, chunk c' = (k>>3) ^ (r&31) -> b128 reads and
// b64 writes both at bank floor.

#define K_DIM 256
#define O_DIM 256
#define BK 32

typedef __attribute__((ext_vector_type(8))) __bf16 bf16x8;
typedef __attribute__((ext_vector_type(4))) float f32x4;
typedef __attribute__((ext_vector_type(4))) unsigned int u32x4;
typedef __attribute__((ext_vector_type(2))) unsigned int u32x2;

__device__ __forceinline__ f32x4 MFMA(u32x4 a, u32x4 b, f32x4 c) {
    return __builtin_amdgcn_mfma_f32_16x16x32_bf16(
        __builtin_bit_cast(bf16x8, a), __builtin_bit_cast(bf16x8, b), c, 0, 0, 0);
}

__device__ __forceinline__ unsigned pk2(float a, float b) {
    __hip_bfloat16 ha = __float2bfloat16(a);
    __hip_bfloat16 hb = __float2bfloat16(b);
    unsigned short sa, sb;
    __builtin_memcpy(&sa, &ha, 2);
    __builtin_memcpy(&sb, &hb, 2);
    return (unsigned)sa | ((unsigned)sb << 16);
}

// B^T tile (o 0..255 rows, k 0..31): 64 row-pairs of 128B, XOR swizzle.
__device__ __forceinline__ int swz(int row, int k) {
    const int rp = row >> 1;
    const int ch = (((row & 1) << 2) + (k >> 3)) ^ (rp & 7);
    return rp * 128 + ch * 16 + (k & 7) * 2;
}

__global__ __launch_bounds__(256) void argemm_kernel(
    const float* __restrict__ x,
    const int* __restrict__ idx,
    const float* __restrict__ w,
    const float* __restrict__ bias,
    float* __restrict__ out)
{
    __shared__ __align__(16) char lds[65536];  // A panel 32KB | B^T dbuf 2x16KB

    const int tid = threadIdx.x;
    const int l   = tid & 63;
    const int wid = tid >> 6;
    const int wr  = wid >> 1;   // 32-row half of the 64-row tile
    const int wc  = wid & 1;    // 128-col half of the 256-col tile

    // XCD-chunked swizzle: the 4 row-tiles of one b are logically adjacent ->
    // same XCD -> w[c] shared in that XCD's L2.
    const unsigned bid     = blockIdx.x;
    const unsigned chunk   = gridDim.x >> 3;
    const unsigned logical = (bid & 7u) * chunk + (bid >> 3);
    const int b  = (int)(logical >> 2);
    const int n0 = (int)(logical & 3u) * 64;

    const int g = l >> 4;   // 0..3 (k-subgroup)
    const int i = l & 15;   // 0..15

    const int c = idx[b];
    const float* xb = x + (size_t)b * (256 * 256);
    const float* wb = w + (size_t)c * (256 * 256);

    // ---- B staging maps (R6 pattern, widened to 256 o) ----
    const int kq = tid >> 5;          // 0..7
    const int m4 = (tid & 31) * 4;    // o-quad 0..124 (low half; +128 high)
    int gB[4], bWlo[4], bWhi[4];
#pragma unroll
    for (int dk = 0; dk < 4; ++dk)
        gB[dk] = (kq * 4 + dk) * O_DIM + m4;           // f32 elem offset
#pragma unroll
    for (int j = 0; j < 4; ++j) {
        bWlo[j] = swz(m4 + j,       kq * 4);
        bWhi[j] = swz(128 + m4 + j, kq * 4);
    }

    // ---- fragment read addresses ----
    int bR[8];
#pragma unroll
    for (int n = 0; n < 8; ++n)
        bR[n] = swz(wc * 128 + n * 16 + i, g * 8);
    int aRow[2], aKey[2];
#pragma unroll
    for (int m = 0; m < 2; ++m) {
        const int r = wr * 32 + m * 16 + i;
        aRow[m] = r * 512;
        aKey[m] = r & 31;
    }

    // ---- two named B staging sets: tile T -> set T&1 ----
    f32x4 rb[2][8];   // [set][dk<4 = lo half o, dk+4 = hi half o]

    auto issueB = [&](int t, int s) {
#pragma unroll
        for (int dk = 0; dk < 4; ++dk) {
            rb[s][dk]     = *(const f32x4*)(wb + gB[dk] + t * (BK * O_DIM));
            rb[s][dk + 4] = *(const f32x4*)(wb + gB[dk] + t * (BK * O_DIM) + 128);
        }
    };
    auto flushB = [&](int T, int s) {
        char* base = (char*)lds + 32768 + (T & 1) * 16384;
#pragma unroll
        for (int j = 0; j < 4; ++j) {
            u32x2 p;                                    // pack along k
            p.x = pk2(rb[s][0][j], rb[s][1][j]);
            p.y = pk2(rb[s][2][j], rb[s][3][j]);
            *(u32x2*)(base + bWlo[j]) = p;
            u32x2 q;
            q.x = pk2(rb[s][4][j], rb[s][5][j]);
            q.y = pk2(rb[s][6][j], rb[s][7][j]);
            *(u32x2*)(base + bWhi[j]) = q;
        }
    };

    // ---- prologue: B tiles 0,1 in flight; A panel staged (sequential) ----
    issueB(0, 0);
    __builtin_amdgcn_sched_barrier(0);
    issueB(1, 1);
    __builtin_amdgcn_sched_barrier(0);

    // A: wave stages rows wid*16 .. wid*16+16; one full 1KB row per instr.
    {
        const float* xw = xb + (n0 + wid * 16) * 256 + l * 4;
        const int csw = l >> 1;            // k-chunk this lane holds (16B f32 -> 8B bf16)
        const int sub = (l & 1) * 8;
        f32x4 xa[8];
#pragma unroll
        for (int s2 = 0; s2 < 2; ++s2) {
#pragma unroll
            for (int j = 0; j < 8; ++j)
                xa[j] = *(const f32x4*)(xw + (s2 * 8 + j) * 256);
            __builtin_amdgcn_sched_barrier(0);
#pragma unroll
            for (int j = 0; j < 8; ++j) {
                const int r = wid * 16 + s2 * 8 + j;
                u32x2 p;
                p.x = pk2(xa[j].x, xa[j].y);
                p.y = pk2(xa[j].z, xa[j].w);
                *(u32x2*)((char*)lds + r * 512 + ((csw ^ (r & 31)) << 4) + sub) = p;
            }
        }
    }

    flushB(0, 0);
    issueB(2, 0);
    __builtin_amdgcn_sched_barrier(0);
    asm volatile("s_waitcnt lgkmcnt(0)" ::: "memory");
    __builtin_amdgcn_sched_barrier(0);
    __builtin_amdgcn_s_barrier();

    f32x4 acc[2][8];
#pragma unroll
    for (int m = 0; m < 2; ++m)
#pragma unroll
        for (int n = 0; n < 8; ++n)
            acc[m][n] = (f32x4){0.f, 0.f, 0.f, 0.f};

    // ---- K loop: 8 rounds; rounds touch only LDS (A) and L2-resident w (B) ----
#pragma unroll
    for (int t = 0; t < 8; ++t) {
        const char* bbuf = (const char*)lds + 32768 + (t & 1) * 16384;

        u32x4 af[2];
#pragma unroll
        for (int m = 0; m < 2; ++m)
            af[m] = *(const u32x4*)((const char*)lds + aRow[m]
                                    + (((t * 4 + g) ^ aKey[m]) << 4));
#pragma unroll
        for (int n = 0; n < 8; ++n) {
            const u32x4 bq = *(const u32x4*)(bbuf + bR[n]);
#pragma unroll
            for (int m = 0; m < 2; ++m)
                acc[m][n] = MFMA(af[m], bq, acc[m][n]);
        }

        if (t < 7) {
            flushB(t + 1, (t + 1) & 1);   // loads issued 2 rounds ago
            if (t < 5) {
                issueB(t + 3, (t + 1) & 1);
                __builtin_amdgcn_sched_barrier(0);   // forbid load sinking (R5/R7 lesson)
            }
            asm volatile("s_waitcnt lgkmcnt(0)" ::: "memory");
            __builtin_amdgcn_sched_barrier(0);
            __builtin_amdgcn_s_barrier();
        }
    }

    // ---- epilogue: bias + LeakyReLU(0.2), f32 store ----
    float biasf[8];
#pragma unroll
    for (int n = 0; n < 8; ++n)
        biasf[n] = bias[wc * 128 + n * 16 + i];

    float* ob = out + (size_t)b * (256 * 256);
#pragma unroll
    for (int m = 0; m < 2; ++m) {
#pragma unroll
        for (int r = 0; r < 4; ++r) {
            const int row = n0 + wr * 32 + m * 16 + g * 4 + r;
#pragma unroll
            for (int n = 0; n < 8; ++n) {
                float v = acc[m][n][r] + biasf[n];
                v = (v >= 0.f) ? v : 0.2f * v;
                ob[row * 256 + wc * 128 + n * 16 + i] = v;
            }
        }
    }
}

extern "C" void kernel_launch(void* const* d_in, const int* in_sizes, int n_in,
                              void* d_out, int out_size, void* d_ws, size_t ws_size,
                              hipStream_t stream) {
    const float* x    = (const float*)d_in[0];
    const int*   idx  = (const int*)d_in[1];
    const float* w    = (const float*)d_in[2];
    const float* bias = (const float*)d_in[3];
    float*       out  = (float*)d_out;
    (void)d_ws; (void)ws_size; (void)n_in; (void)out_size;

    const int B = in_sizes[1];          // 2048
    dim3 grid((unsigned)(B * 4)), block(256);
    hipLaunchKernelGGL(argemm_kernel, grid, block, 0, stream, x, idx, w, bias, out);
}

// Round 7
// 294.098 us; speedup vs baseline: 2.4388x; 1.0023x over previous
//
#include <hip/hip_runtime.h>
#include <hip/hip_bf16.h>

// AdaptiveReLULayer: out[b,n,o] = leaky( sum_i x[b,n,i] * weight[idx[b],i,o] + bias[o], 0.2 )
// B=2048, N=256, IN=256, OUT=256, C=1024.  f32 I/O; bf16 MFMA, f32 accum.
//
// R9 (fixed compile: flushX takes only the set index) vs R8 (295us):
// the only unvaried axis is L2/L3 *weight* traffic. R8 moved w over the
// fabric 4x per batch (2.1 GB) concurrent with the 1.07 GB HBM stream
// (total ~10.8 TB/s through TCC). R9 makes EVERY stream minimal and
// sequential simultaneously:
//   * grid = 2048 (one block per batch b), 512 threads = 8 waves
//   * w[idx[b]] staged ONCE: 256KB sequential L3 read -> bf16 B^T panel in
//     128KB LDS (depth-2 reg-staged passes); each wave then extracts its
//     32-col B-fragments into 64 VGPRs ONCE (16 ds_read_b128)
//   * x: 8 n-slabs of 32 rows; slab = contiguous 32KB HBM read, depth-2
//     reg-staged (R6/R8-proven named sets + sched_barrier anti-sinking)
//   * K-path touches only LDS(A) + VGPR(B); w fabric traffic = 537 MB total
//     (1x), x = 537 MB HBM, out = 524 MB HBM
//   * LDS = 128KB w + 16KB A slab = 144KB -> 1 block/CU (occupancy proven
//     non-binding in R4)
// Panel layout (both w-cols and A-rows): row = 512B, 16B chunk index
// (k>>3) ^ (row&7) -> frag reads at uniform 8-access/bank-quad floor.

typedef __attribute__((ext_vector_type(8))) __bf16 bf16x8;
typedef __attribute__((ext_vector_type(4))) float f32x4;
typedef __attribute__((ext_vector_type(4))) unsigned int u32x4;
typedef __attribute__((ext_vector_type(2))) unsigned int u32x2;

#define AOFF 131072   // A slab panel base (after 128KB w panel)

__device__ __forceinline__ f32x4 MFMA(u32x4 a, u32x4 b, f32x4 c) {
    return __builtin_amdgcn_mfma_f32_16x16x32_bf16(
        __builtin_bit_cast(bf16x8, a), __builtin_bit_cast(bf16x8, b), c, 0, 0, 0);
}

__device__ __forceinline__ unsigned pk2(float a, float b) {
    __hip_bfloat16 ha = __float2bfloat16(a);
    __hip_bfloat16 hb = __float2bfloat16(b);
    unsigned short sa, sb;
    __builtin_memcpy(&sa, &ha, 2);
    __builtin_memcpy(&sb, &hb, 2);
    return (unsigned)sa | ((unsigned)sb << 16);
}

__global__ __launch_bounds__(512, 2) void argemm_kernel(
    const float* __restrict__ x,
    const int* __restrict__ idx,
    const float* __restrict__ w,
    const float* __restrict__ bias,
    float* __restrict__ out)
{
    __shared__ __align__(16) char lds[147456];  // w B^T panel 128KB | A slab 16KB

    const int tid = threadIdx.x;
    const int l   = tid & 63;
    const int wid = tid >> 6;        // 0..7: wave owns output cols wid*32..+31
    const int g   = l >> 4;          // 0..3 (k-subgroup)
    const int i   = l & 15;          // 0..15
    const int ikey = i & 7;

    // XCD-chunked swizzle (gridDim.x % 8 == 0): consecutive b's share an XCD
    const unsigned bid   = blockIdx.x;
    const unsigned chunk = gridDim.x >> 3;
    const int b = (int)((bid & 7u) * chunk + (bid >> 3));

    const int c = idx[b];
    const float* xb = x + (size_t)b * (256 * 256);
    const float* wb = w + (size_t)c * (256 * 256);

    // ---- w prologue staging map: pass p covers k = p*32 .. p*32+31 ----
    // thread: col-quad q = l (cols q*4..+3), k-subrow kg = wid (k = p*32+kg*4+dk)
    const int q  = l;
    const int kg = wid;
    const int c0 = kg >> 1;               // chunk contribution of kg
    int wWb[4], wKey[4];
#pragma unroll
    for (int j = 0; j < 4; ++j) {
        wWb[j]  = (q * 4 + j) * 512 + (kg & 1) * 8;
        wKey[j] = (q * 4 + j) & 7;
    }

    // ---- x slab staging map: row = tid>>4 (0..31), k0 = (tid&15)*16 ----
    const int xrow = tid >> 4;
    const int xk0  = (tid & 15) * 16;
    const float* xg = xb + xrow * 256 + xk0;
    const int aW0 = AOFF + xrow * 512 + ((((xk0 >> 3) + 0) ^ (xrow & 7)) << 4);
    const int aW1 = AOFF + xrow * 512 + ((((xk0 >> 3) + 1) ^ (xrow & 7)) << 4);

    // ---- fragment read bases ----
    int aBase[2];
#pragma unroll
    for (int m = 0; m < 2; ++m) aBase[m] = AOFF + (m * 16 + i) * 512;
    int bBase[2];
#pragma unroll
    for (int n = 0; n < 2; ++n) bBase[n] = (wid * 32 + n * 16 + i) * 512;

    float biasf[2];
#pragma unroll
    for (int n = 0; n < 2; ++n) biasf[n] = bias[wid * 32 + n * 16 + i];

    // ---- staging register sets ----
    f32x4 xs[2][4];   // x slab sets (depth-2)
    f32x4 rw[2][4];   // w pass sets (depth-2, prologue only)

    auto issueX = [&](int s, int ss) {
#pragma unroll
        for (int d = 0; d < 4; ++d)
            xs[ss][d] = *(const f32x4*)(xg + s * 8192 + d * 4);
    };
    auto flushX = [&](int ss) {
        u32x4 p0, p1;
        p0.x = pk2(xs[ss][0].x, xs[ss][0].y); p0.y = pk2(xs[ss][0].z, xs[ss][0].w);
        p0.z = pk2(xs[ss][1].x, xs[ss][1].y); p0.w = pk2(xs[ss][1].z, xs[ss][1].w);
        p1.x = pk2(xs[ss][2].x, xs[ss][2].y); p1.y = pk2(xs[ss][2].z, xs[ss][2].w);
        p1.z = pk2(xs[ss][3].x, xs[ss][3].y); p1.w = pk2(xs[ss][3].z, xs[ss][3].w);
        *(u32x4*)((char*)lds + aW0) = p0;
        *(u32x4*)((char*)lds + aW1) = p1;
    };
    auto issueW = [&](int p, int ss) {
#pragma unroll
        for (int dk = 0; dk < 4; ++dk)
            rw[ss][dk] = *(const f32x4*)(wb + (p * 32 + kg * 4 + dk) * 256 + q * 4);
    };
    auto flushW = [&](int p, int ss) {
#pragma unroll
        for (int j = 0; j < 4; ++j) {
            u32x2 pr;                      // k-contiguous 4 bf16 for col q*4+j
            pr.x = pk2(rw[ss][0][j], rw[ss][1][j]);
            pr.y = pk2(rw[ss][2][j], rw[ss][3][j]);
            *(u32x2*)((char*)lds + wWb[j] + (((p * 4 + c0) ^ wKey[j]) << 4)) = pr;
        }
    };

    // ---- prologue: x(0),x(1) oldest in queue; then 8 w passes (depth-2) ----
    issueX(0, 0);
    issueX(1, 1);
    __builtin_amdgcn_sched_barrier(0);
    issueW(0, 0);
    __builtin_amdgcn_sched_barrier(0);
    issueW(1, 1);
    __builtin_amdgcn_sched_barrier(0);
#pragma unroll
    for (int p = 0; p < 8; ++p) {
        flushW(p, p & 1);
        if (p < 6) {
            issueW(p + 2, p & 1);
            __builtin_amdgcn_sched_barrier(0);
        }
    }
    asm volatile("s_waitcnt lgkmcnt(0)" ::: "memory");
    __builtin_amdgcn_sched_barrier(0);
    __builtin_amdgcn_s_barrier();          // w panel visible to all waves

    // ---- extract this wave's B fragments ONCE: 16 x ds_read_b128 -> 64 VGPR ----
    u32x4 bReg[16];
#pragma unroll
    for (int t = 0; t < 8; ++t)
#pragma unroll
        for (int n = 0; n < 2; ++n)
            bReg[t * 2 + n] = *(const u32x4*)((const char*)lds + bBase[n]
                                              + (((t * 4 + g) ^ ikey) << 4));
    __builtin_amdgcn_sched_barrier(0);

    flushX(0);                             // waits x(0) via counted vmcnt
    asm volatile("s_waitcnt lgkmcnt(0)" ::: "memory");
    __builtin_amdgcn_sched_barrier(0);
    __builtin_amdgcn_s_barrier();          // A(0) visible

    float* ob = out + (size_t)b * (256 * 256) + wid * 32;

    // ---- n-slab loop: K-path touches only LDS(A) + VGPR(B) ----
#pragma unroll
    for (int s = 0; s < 8; ++s) {
        if (s < 6) {
            issueX(s + 2, s & 1);          // set s&1 freed by flushX(s)
            __builtin_amdgcn_sched_barrier(0);
        }

        f32x4 acc[2][2];
#pragma unroll
        for (int m = 0; m < 2; ++m)
#pragma unroll
            for (int n = 0; n < 2; ++n)
                acc[m][n] = (f32x4){0.f, 0.f, 0.f, 0.f};

#pragma unroll
        for (int t = 0; t < 8; ++t) {
            const int off = ((t * 4 + g) ^ ikey) << 4;
            const u32x4 af0 = *(const u32x4*)((const char*)lds + aBase[0] + off);
            const u32x4 af1 = *(const u32x4*)((const char*)lds + aBase[1] + off);
            acc[0][0] = MFMA(af0, bReg[t * 2 + 0], acc[0][0]);
            acc[0][1] = MFMA(af0, bReg[t * 2 + 1], acc[0][1]);
            acc[1][0] = MFMA(af1, bReg[t * 2 + 0], acc[1][0]);
            acc[1][1] = MFMA(af1, bReg[t * 2 + 1], acc[1][1]);
        }

        // stores (fire-and-forget; drain across barriers)
#pragma unroll
        for (int m = 0; m < 2; ++m)
#pragma unroll
            for (int r = 0; r < 4; ++r) {
                const int row = s * 32 + m * 16 + g * 4 + r;
#pragma unroll
                for (int n = 0; n < 2; ++n) {
                    float v = acc[m][n][r] + biasf[n];
                    v = (v >= 0.f) ? v : 0.2f * v;
                    ob[row * 256 + n * 16 + i] = v;
                }
            }

        asm volatile("s_waitcnt lgkmcnt(0)" ::: "memory");   // af reads retired
        __builtin_amdgcn_sched_barrier(0);
        __builtin_amdgcn_s_barrier();      // all waves done reading A(s)

        if (s < 7) {
            flushX((s + 1) & 1);           // loads issued ~2 slabs ago
            asm volatile("s_waitcnt lgkmcnt(0)" ::: "memory");
            __builtin_amdgcn_sched_barrier(0);
            __builtin_amdgcn_s_barrier();  // A(s+1) visible
        }
    }
}

extern "C" void kernel_launch(void* const* d_in, const int* in_sizes, int n_in,
                              void* d_out, int out_size, void* d_ws, size_t ws_size,
                              hipStream_t stream) {
    const float* x    = (const float*)d_in[0];
    const int*   idx  = (const int*)d_in[1];
    const float* w    = (const float*)d_in[2];
    const float* bias = (const float*)d_in[3];
    float*       out  = (float*)d_out;
    (void)d_ws; (void)ws_size; (void)n_in; (void)out_size;

    const int B = in_sizes[1];          // 2048
    dim3 grid((unsigned)B), block(512);
    hipLaunchKernelGGL(argemm_kernel, grid, block, 0, stream, x, idx, w, bias, out);
}